// Round 9
// baseline (408.711 us; speedup 1.0000x reference)
//
#include <hip/hip_runtime.h>
#include <math.h>

#define SB 4
#define CC 48
#define NH 8
#define HDIM 6
#define NPIX 4096
#define NE 16
#define TD 512

__device__ __forceinline__ float wave_sum(float t){
#pragma unroll
  for (int o = 32; o >= 1; o >>= 1) t += __shfl_xor(t, o, 64);
  return t;
}

__device__ __forceinline__ float gelu(float t){
  return 0.5f*t*(1.f + erff(t*0.70710678118654752f));
}

// acc[8] += z * w-row (2 float4 in scope: _w0,_w1)
#define ACC8(A, Z) { float _z=(Z); \
  A[0]+=_z*_w0.x; A[1]+=_z*_w0.y; A[2]+=_z*_w0.z; A[3]+=_z*_w0.w; \
  A[4]+=_z*_w1.x; A[5]+=_z*_w1.y; A[6]+=_z*_w1.z; A[7]+=_z*_w1.w; }

// ---------------- K1: LN1 + qkv/router 1x1, 6 oc-sections, 1 px/thread ----------
__global__ __launch_bounds__(256) void k_ln_qkv(
    const float* __restrict__ x, const float* __restrict__ ln1w, const float* __restrict__ ln1b,
    const float* __restrict__ qkvw, const float* __restrict__ routw,
    float* __restrict__ qkv_raw, float* __restrict__ rl)
{
  int sec = blockIdx.z;
  int NOC = (sec == 5) ? 32 : 24;
  __shared__ __align__(16) float wl[32*48];
  int tid = threadIdx.x;
  for (int i = tid; i < NOC*48; i += 256){
    int oc = i/48, c = i%48, og = sec*24 + oc;
    wl[i] = (og < 144) ? qkvw[og*48 + c] : routw[(og-144)*48 + c];
  }
  __syncthreads();
  int b = blockIdx.y;
  int p = blockIdx.x*256 + tid;
  const float* xb = x + (size_t)b*CC*NPIX;
  float v[48];
  float mu = 0.f;
#pragma unroll
  for (int c = 0; c < CC; c++){ v[c] = xb[(size_t)c*NPIX + p]; mu += v[c]; }
  mu *= (1.f/CC);
  float va = 0.f;
#pragma unroll
  for (int c = 0; c < CC; c++){ float d = v[c]-mu; va += d*d; }
  float rs = rsqrtf(va*(1.f/CC) + 1e-5f);
#pragma unroll
  for (int c = 0; c < CC; c++) v[c] = (v[c]-mu)*rs*ln1w[c] + ln1b[c];
  float* qb = qkv_raw + (size_t)b*144*NPIX;
  float* rb = rl + (size_t)b*NH*NPIX;
  for (int oc = 0; oc < NOC; oc++){
    const float4* wv = (const float4*)&wl[oc*48];
    float s = 0.f;
#pragma unroll
    for (int q = 0; q < 12; q++){
      float4 w = wv[q];
      s += w.x*v[q*4] + w.y*v[q*4+1] + w.z*v[q*4+2] + w.w*v[q*4+3];
    }
    int og = sec*24 + oc;
    float* dst = (og < 144) ? (qb + (size_t)og*NPIX) : (rb + (size_t)(og-144)*NPIX);
    dst[p] = s;
  }
}

// ---------------- K2: depthwise 3x3, pad 1 --------------------------------------
__global__ __launch_bounds__(256) void k_dwconv(
    const float* __restrict__ in, const float* __restrict__ w, float* __restrict__ out)
{
  int ch = blockIdx.y, b = blockIdx.z;
  int p = blockIdx.x*256 + threadIdx.x;
  int y = p >> 6, xx = p & 63;
  const float* wc = w + ch*9;
  const float* ib = in + ((size_t)b*144 + ch)*NPIX;
  float acc = 0.f;
#pragma unroll
  for (int ky = 0; ky < 3; ky++){
    int yy = y + ky - 1;
    if ((unsigned)yy < 64u){
#pragma unroll
      for (int kx = 0; kx < 3; kx++){
        int xc = xx + kx - 1;
        if ((unsigned)xc < 64u) acc += wc[ky*3+kx]*ib[yy*64+xc];
      }
    }
  }
  out[((size_t)b*144 + ch)*NPIX + p] = acc;
}

// ---------------- K3: per-pixel head routing ------------------------------------
__global__ __launch_bounds__(256) void k_router_gates(
    const float* __restrict__ rl, float* __restrict__ g)
{
  int idx = blockIdx.x*256 + threadIdx.x;
  int b = idx >> 12, p = idx & (NPIX-1);
  const float* r = rl + (size_t)b*NH*NPIX + p;
  float l[NH];
  float mx = -1e30f;
#pragma unroll
  for (int h = 0; h < NH; h++){ l[h] = r[(size_t)h*NPIX]; mx = fmaxf(mx, l[h]); }
  float s = 0.f;
#pragma unroll
  for (int h = 0; h < NH; h++){ l[h] = __expf(l[h]-mx); s += l[h]; }
  int i1 = 0; float p1 = -1.f;
#pragma unroll
  for (int h = 0; h < NH; h++) if (l[h] > p1){ p1 = l[h]; i1 = h; }
  int i2 = -1; float p2 = -1.f;
#pragma unroll
  for (int h = 0; h < NH; h++) if (h != i1 && l[h] > p2){ p2 = l[h]; i2 = h; }
  float denom = p1 + p2;
  float* go = g + (size_t)b*NH*NPIX + p;
#pragma unroll
  for (int h = 0; h < NH; h++)
    go[(size_t)h*NPIX] = (h == i1 || h == i2) ? l[h]/denom : 0.f;
}

// ---------------- attention phase A: partial gram/norm sums ---------------------
__global__ __launch_bounds__(256) void k_attn_part(
    const float* __restrict__ qkv, float* __restrict__ part)
{
  int ch = blockIdx.x, h = blockIdx.y, b = blockIdx.z;
  const float* q = qkv + ((size_t)b*144 + h*HDIM)*NPIX;
  const float* k = qkv + ((size_t)b*144 + 48 + h*HDIM)*NPIX;
  int tid = threadIdx.x;
  float qq[HDIM] = {0}, kk[HDIM] = {0}, qk[HDIM*HDIM] = {0};
#pragma unroll
  for (int t = 0; t < 2; t++){
    int n = ch*512 + t*256 + tid;
    float qv[HDIM], kv[HDIM];
#pragma unroll
    for (int c = 0; c < HDIM; c++){ qv[c] = q[(size_t)c*NPIX + n]; kv[c] = k[(size_t)c*NPIX + n]; }
#pragma unroll
    for (int c = 0; c < HDIM; c++){
      qq[c] += qv[c]*qv[c]; kk[c] += kv[c]*kv[c];
#pragma unroll
      for (int d = 0; d < HDIM; d++) qk[c*HDIM+d] += qv[c]*kv[d];
    }
  }
#pragma unroll
  for (int c = 0; c < HDIM; c++){ qq[c] = wave_sum(qq[c]); kk[c] = wave_sum(kk[c]); }
#pragma unroll
  for (int i = 0; i < HDIM*HDIM; i++) qk[i] = wave_sum(qk[i]);
  __shared__ float red[4][48];
  int lane = tid & 63, wv = tid >> 6;
  if (lane == 0){
#pragma unroll
    for (int c = 0; c < HDIM; c++){ red[wv][c] = qq[c]; red[wv][6+c] = kk[c]; }
#pragma unroll
    for (int i = 0; i < HDIM*HDIM; i++) red[wv][12+i] = qk[i];
  }
  __syncthreads();
  if (tid < 48)
    part[((size_t)(b*NH+h)*8 + ch)*48 + tid] = red[0][tid]+red[1][tid]+red[2][tid]+red[3][tid];
}

// ---------------- attention phase B: softmax matrix -----------------------------
__global__ __launch_bounds__(64) void k_attn_soft(
    const float* __restrict__ part, float* __restrict__ smg)
{
  int h = blockIdx.x, b = blockIdx.y, tid = threadIdx.x;
  __shared__ float tot[48];
  if (tid < 48){
    float s = 0.f;
    for (int ch = 0; ch < 8; ch++) s += part[((size_t)(b*NH+h)*8 + ch)*48 + tid];
    tot[tid] = s;
  }
  __syncthreads();
  if (tid < HDIM){
    int c = tid;
    float qn = fmaxf(sqrtf(tot[c]), 1e-12f);
    float row[HDIM];
    float mx = -1e30f;
#pragma unroll
    for (int d = 0; d < HDIM; d++){
      float kn = fmaxf(sqrtf(tot[6+d]), 1e-12f);
      float a = tot[12 + c*HDIM + d] / (qn*kn) * 0.40824829046386307f;
      row[d] = a; mx = fmaxf(mx, a);
    }
    float s = 0.f;
#pragma unroll
    for (int d = 0; d < HDIM; d++){ row[d] = __expf(row[d]-mx); s += row[d]; }
#pragma unroll
    for (int d = 0; d < HDIM; d++) smg[(size_t)(b*NH+h)*36 + c*HDIM + d] = row[d]/s;
  }
}

// ---------------- attention phase C: apply sm·v × gate --------------------------
__global__ __launch_bounds__(256) void k_attn_apply(
    const float* __restrict__ qkv, const float* __restrict__ smg,
    const float* __restrict__ g, float* __restrict__ out)
{
  int h = blockIdx.y, b = blockIdx.z;
  __shared__ float sm[36];
  int tid = threadIdx.x;
  if (tid < 36) sm[tid] = smg[(size_t)(b*NH+h)*36 + tid];
  __syncthreads();
  int n = blockIdx.x*256 + tid;
  const float* v = qkv + ((size_t)b*144 + 96 + h*HDIM)*NPIX;
  float vv[HDIM];
#pragma unroll
  for (int d = 0; d < HDIM; d++) vv[d] = v[(size_t)d*NPIX + n];
  float gg = g[((size_t)b*NH + h)*NPIX + n];
  float* ob = out + ((size_t)b*CC + h*HDIM)*NPIX;
#pragma unroll
  for (int c = 0; c < HDIM; c++){
    float o = 0.f;
#pragma unroll
    for (int d = 0; d < HDIM; d++) o += sm[c*HDIM+d]*vv[d];
    ob[(size_t)c*NPIX + n] = o*gg;
  }
}

// ---------------- K5: proj 1x1 + residual + LN2 (64-thread blocks) --------------
__global__ __launch_bounds__(64) void k_proj_ln2(
    const float* __restrict__ attn_out, const float* __restrict__ x,
    const float* __restrict__ projw, const float* __restrict__ ln2w, const float* __restrict__ ln2b,
    float* __restrict__ xout, float* __restrict__ y2)
{
  __shared__ __align__(16) float w[CC*CC];
  int tid = threadIdx.x;
  for (int i = tid; i < CC*CC; i += 64) w[i] = projw[i];
  __syncthreads();
  int b = blockIdx.y;
  int p = blockIdx.x*64 + tid;
  const float* ain = attn_out + (size_t)b*CC*NPIX + p;
  float a[CC];
#pragma unroll
  for (int c = 0; c < CC; c++) a[c] = ain[(size_t)c*NPIX];
  const float* xb = x + (size_t)b*CC*NPIX + p;
  float xv[CC];
  float mu = 0.f;
#pragma unroll
  for (int oc = 0; oc < CC; oc++){
    const float4* wr = (const float4*)&w[oc*CC];
    float acc = 0.f;
#pragma unroll
    for (int q = 0; q < 12; q++){
      float4 ww = wr[q];
      acc += ww.x*a[q*4] + ww.y*a[q*4+1] + ww.z*a[q*4+2] + ww.w*a[q*4+3];
    }
    float t = xb[(size_t)oc*NPIX] + acc;
    xv[oc] = t; mu += t;
  }
  mu *= (1.f/CC);
  float var = 0.f;
#pragma unroll
  for (int c = 0; c < CC; c++){ float d = xv[c]-mu; var += d*d; }
  var *= (1.f/CC);
  float rs = rsqrtf(var + 1e-5f);
  float* xo = xout + (size_t)b*CC*NPIX + p;
  float* yo = y2 + (size_t)b*CC*NPIX + p;
#pragma unroll
  for (int c = 0; c < CC; c++){
    xo[(size_t)c*NPIX] = xv[c];
    yo[(size_t)c*NPIX] = (xv[c]-mu)*rs*ln2w[c] + ln2b[c];
  }
}

// ---------------- K_pool --------------------------------------------------------
__global__ __launch_bounds__(256) void k_pool(const float* __restrict__ y2, float* __restrict__ pooled)
{
  int bc = blockIdx.x;
  const float* r = y2 + (size_t)bc*NPIX;
  float s = 0.f;
  for (int n = threadIdx.x; n < NPIX; n += 256) s += r[n];
  s = wave_sum(s);
  __shared__ float red[4];
  int lane = threadIdx.x & 63, wv = threadIdx.x >> 6;
  if (lane == 0) red[wv] = s;
  __syncthreads();
  if (threadIdx.x == 0) pooled[bc] = (red[0]+red[1]+red[2]+red[3]) * (1.f/NPIX);
}

// ---------------- K6: MoE gate (+ pair compaction) ------------------------------
__global__ __launch_bounds__(64) void k_moe_gate(
    const float* __restrict__ pooled, const float* __restrict__ text,
    const float* __restrict__ gwx, const float* __restrict__ gwt,
    float* __restrict__ gates, int* __restrict__ pairs)
{
  int tid = threadIdx.x;
  int b = tid >> 4, e = tid & 15;
  float acc = 0.f;
  for (int c = 0; c < CC; c++) acc += pooled[b*CC + c]*gwx[c*NE + e];
  for (int d = 0; d < TD; d++) acc += text[b*TD + d]*gwt[d*NE + e];
  __shared__ float lg[SB][NE];
  lg[b][e] = acc;
  __syncthreads();
  if (tid < SB){
    int bb = tid;
    float mx = -1e30f;
    for (int i = 0; i < NE; i++) mx = fmaxf(mx, lg[bb][i]);
    float ex[NE]; float s = 0.f;
    for (int i = 0; i < NE; i++){ ex[i] = __expf(lg[bb][i]-mx); s += ex[i]; }
    int i1 = 0; float p1 = -1.f;
    for (int i = 0; i < NE; i++) if (ex[i] > p1){ p1 = ex[i]; i1 = i; }
    int i2 = -1; float p2 = -1.f;
    for (int i = 0; i < NE; i++) if (i != i1 && ex[i] > p2){ p2 = ex[i]; i2 = i; }
    float denom = p1 + p2;
    for (int i = 0; i < NE; i++)
      gates[bb*NE + i] = (i == i1 || i == i2) ? ex[i]/denom : 0.f;
    pairs[bb*2 + 0] = bb*NE + i1;
    pairs[bb*2 + 1] = bb*NE + i2;
  }
}

// ================= Expert path (batched h-slot packing) ==========================
__device__ __forceinline__ float* hslot(float* hb, int e, int b, int np){
  int t0c = (e+2)/3, t1c = (e+1)/3, t2c = e/3;
  size_t off = 4u*((size_t)t0c*196608u + (size_t)t1c*786432u + (size_t)t2c*49152u);
  return hb + off + (size_t)b*CC*np;
}

// ---- unified conv1 (+bias+gelu): grid (96, 8 pairs); dbuf patch, 1 barrier/icg --
__global__ __launch_bounds__(256) void k_econv1u(
    const float* __restrict__ y2, const float* __restrict__ w1, const float* __restrict__ b1,
    const int* __restrict__ pairs, float* __restrict__ hbase)
{
  int pe = pairs[blockIdx.y];
  int b = pe >> 4, e = pe & 15, ty = e % 3;
  int nx = (ty == 0) ? 48 : ((ty == 1) ? 96 : 24);
  if ((int)blockIdx.x >= nx) return;
  int ocg = blockIdx.x % 6, band = blockIdx.x / 6, yb = band*8;
  int tid = threadIdx.x;

  __shared__ __align__(16) float smem[3456 + 5200];
  float* wl = smem; float* pa = smem + 3456;
  const float4* wv4 = (const float4*)wl;
  const float* wg = w1 + (size_t)e*CC*CC*9 + (size_t)(ocg*8)*CC*9;
  for (int i = tid; i < 3456; i += 256){
    int ic = i/72, r2 = i%72, k = r2/8, j = r2%8;
    wl[i] = wg[((size_t)j*CC + ic)*9 + k];
  }
  float bb[8];
#pragma unroll
  for (int j = 0; j < 8; j++) bb[j] = b1[e*CC + ocg*8 + j];
  const float* src = y2 + (size_t)b*CC*NPIX;

  if (ty == 0){
    float* hp = hslot(hbase, e, b, 4096);
    int r = tid >> 5, xp = (tid & 31)*2;
    float a0[8], a1[8];
#pragma unroll
    for (int j = 0; j < 8; j++){ a0[j] = bb[j]; a1[j] = bb[j]; }
    int ldso[10], srco[10];
#pragma unroll
    for (int q = 0; q < 10; q++){
      int i = tid + 256*q;
      int icl = i/640, rem = i%640, rr = rem>>6, cc = rem&63;
      int s = yb - 1 + rr;
      ldso[q] = icl*650 + rr*65 + cc;
      srco[q] = ((unsigned)s < 64u) ? (icl*NPIX + s*64 + cc) : -1;
    }
    float st[10];
#pragma unroll
    for (int q = 0; q < 10; q++) st[q] = (srco[q] >= 0) ? src[srco[q]] : 0.f;
#pragma unroll
    for (int q = 0; q < 10; q++) pa[ldso[q]] = st[q];
    __syncthreads();
    for (int icg = 0; icg < 12; icg++){
      if (icg < 11){
        const float* s2 = src + (size_t)(icg+1)*4*NPIX;
#pragma unroll
        for (int q = 0; q < 10; q++) st[q] = (srco[q] >= 0) ? s2[srco[q]] : 0.f;
      }
      const float* pcur = pa + (icg & 1)*2600;
#pragma unroll
      for (int icl = 0; icl < 4; icl++){
        const float* pp = pcur + icl*650 + r*65;
        float zz[3][4];
#pragma unroll
        for (int dy = 0; dy < 3; dy++)
#pragma unroll
          for (int dx = 0; dx < 4; dx++){
            int xx = xp - 1 + dx;
            zz[dy][dx] = ((unsigned)xx < 64u) ? pp[dy*65 + xx] : 0.f;
          }
        int wb = ((icg*4+icl)*9)*2;
#pragma unroll
        for (int k = 0; k < 9; k++){
          float4 _w0 = wv4[wb + k*2], _w1 = wv4[wb + k*2 + 1];
          ACC8(a0, zz[k/3][k%3]);
          ACC8(a1, zz[k/3][k%3+1]);
        }
      }
      if (icg < 11){
        float* pnext = pa + ((icg+1) & 1)*2600;
#pragma unroll
        for (int q = 0; q < 10; q++) pnext[ldso[q]] = st[q];
      }
      __syncthreads();
    }
    int p0 = (yb + r)*64 + xp;
#pragma unroll
    for (int j = 0; j < 8; j++){
      int oc = ocg*8 + j;
      hp[(size_t)oc*4096 + p0]     = gelu(a0[j]);
      hp[(size_t)oc*4096 + p0 + 1] = gelu(a1[j]);
    }
  } else if (ty == 1){
    // 2x2 quad per thread: rows yb+2*qr..+1, cols qx..qx+1
    float* hp = hslot(hbase, e, b, 16384);
    int qr = tid >> 6, qx = (tid & 63)*2;
    float ac[4][8];
#pragma unroll
    for (int i = 0; i < 4; i++)
#pragma unroll
      for (int j = 0; j < 8; j++) ac[i][j] = bb[j];
    int row0 = (yb >> 1) - 1;
    int ldso[6], srco[6];
#pragma unroll
    for (int q = 0; q < 6; q++){
      int i = tid + 256*q;
      int icl = i/384, rem = i%384, rr = rem>>6, cc = rem&63;
      int s = row0 + rr;
      ldso[q] = icl*390 + rr*65 + cc;
      srco[q] = ((unsigned)s < 64u) ? (icl*NPIX + s*64 + cc) : -1;
    }
    float st[6];
#pragma unroll
    for (int q = 0; q < 6; q++) st[q] = (srco[q] >= 0) ? src[srco[q]] : 0.f;
#pragma unroll
    for (int q = 0; q < 6; q++) pa[ldso[q]] = st[q];
    __syncthreads();
    int prw[4];
#pragma unroll
    for (int dy = 0; dy < 4; dy++) prw[dy] = ((2*qr + dy - 1) >> 1) + 1;
    for (int icg = 0; icg < 12; icg++){
      if (icg < 11){
        const float* s2 = src + (size_t)(icg+1)*4*NPIX;
#pragma unroll
        for (int q = 0; q < 6; q++) st[q] = (srco[q] >= 0) ? s2[srco[q]] : 0.f;
      }
      const float* pcur = pa + (icg & 1)*1560;
#pragma unroll
      for (int icl = 0; icl < 4; icl++){
        const float* pp = pcur + icl*390;
        float zz[4][4];
#pragma unroll
        for (int dy = 0; dy < 4; dy++)
#pragma unroll
          for (int dx = 0; dx < 4; dx++){
            int xx = qx + dx - 1;
            zz[dy][dx] = ((unsigned)xx < 128u) ? pp[prw[dy]*65 + (xx>>1)] : 0.f;
          }
        int wb = ((icg*4+icl)*9)*2;
#pragma unroll
        for (int k = 0; k < 9; k++){
          float4 _w0 = wv4[wb + k*2], _w1 = wv4[wb + k*2 + 1];
          int ky = k/3, kx = k%3;
          ACC8(ac[0], zz[ky][kx]);
          ACC8(ac[1], zz[ky][kx+1]);
          ACC8(ac[2], zz[ky+1][kx]);
          ACC8(ac[3], zz[ky+1][kx+1]);
        }
      }
      if (icg < 11){
        float* pnext = pa + ((icg+1) & 1)*1560;
#pragma unroll
        for (int q = 0; q < 6; q++) pnext[ldso[q]] = st[q];
      }
      __syncthreads();
    }
#pragma unroll
    for (int i = 0; i < 4; i++){
      int p = (yb + 2*qr + (i>>1))*128 + qx + (i&1);
#pragma unroll
      for (int j = 0; j < 8; j++)
        hp[(size_t)(ocg*8 + j)*16384 + p] = gelu(ac[i][j]);
    }
  } else {
    float* hp = hslot(hbase, e, b, 1024);
    int r = tid >> 5, xp = tid & 31;
    float ac[8];
#pragma unroll
    for (int j = 0; j < 8; j++) ac[j] = bb[j];
    int row0 = 2*yb - 2;
    int ldso[10], srco[10];
#pragma unroll
    for (int q = 0; q < 10; q++){
      int i = tid + 256*q;
      int icl = i/1280, rem = i%1280, rr = rem>>6, cc = rem&63;
      int s = row0 + rr;
      ldso[q] = icl*1300 + rr*65 + cc;
      srco[q] = ((unsigned)s < 64u) ? (icl*NPIX + s*64 + cc) : -1;
    }
    float st[10];
#pragma unroll
    for (int q = 0; q < 10; q++) st[q] = (srco[q] >= 0) ? src[srco[q]] : 0.f;
#pragma unroll
    for (int q = 0; q < 10; q++) pa[ldso[q]] = st[q];
    __syncthreads();
    for (int icg = 0; icg < 24; icg++){
      if (icg < 23){
        const float* s2 = src + (size_t)(icg+1)*2*NPIX;
#pragma unroll
        for (int q = 0; q < 10; q++) st[q] = (srco[q] >= 0) ? s2[srco[q]] : 0.f;
      }
      const float* pcur = pa + (icg & 1)*2600;
#pragma unroll
      for (int icl = 0; icl < 2; icl++){
        const float* pp = pcur + icl*1300;
        float zz[3][3];
#pragma unroll
        for (int dy = 0; dy < 3; dy++){
          int sy = yb + r + dy - 1;
          int pr2 = 2*(r + dy - 1) + 2;
#pragma unroll
          for (int dx = 0; dx < 3; dx++){
            int sx = xp + dx - 1;
            float m = 0.f;
            if ((unsigned)sy < 32u && (unsigned)sx < 32u){
              int c2 = 2*sx;
              m = fmaxf(fmaxf(pp[pr2*65+c2], pp[pr2*65+c2+1]),
                        fmaxf(pp[(pr2+1)*65+c2], pp[(pr2+1)*65+c2+1]));
            }
            zz[dy][dx] = m;
          }
        }
        int wb = ((icg*2+icl)*9)*2;
#pragma unroll
        for (int k = 0; k < 9; k++){
          float4 _w0 = wv4[wb + k*2], _w1 = wv4[wb + k*2 + 1];
          ACC8(ac, zz[k/3][k%3]);
        }
      }
      if (icg < 23){
        float* pnext = pa + ((icg+1) & 1)*2600;
#pragma unroll
        for (int q = 0; q < 10; q++) pnext[ldso[q]] = st[q];
      }
      __syncthreads();
    }
    int p = (yb + r)*32 + xp;
#pragma unroll
    for (int j = 0; j < 8; j++)
      hp[(size_t)(ocg*8 + j)*1024 + p] = gelu(ac[j]);
  }
}

// ---- unified conv2 (+bias, fused tails): grid (96, 8 pairs); dbuf patch ---------
__device__ __forceinline__ void bl_coord(int o, int& i0, int& i1, float& w0, float& w1){
  float f = 0.5f*o - 0.25f;
  float fl = floorf(f);
  int i = (int)fl;
  float fr = f - fl;
  i0 = i < 0 ? 0 : i;
  int j = i + 1;
  i1 = j > 31 ? 31 : j;
  w0 = 1.f - fr; w1 = fr;
}

__global__ __launch_bounds__(256) void k_econv2u(
    const float* __restrict__ hbase, const float* __restrict__ w2, const float* __restrict__ b2,
    const float* __restrict__ gates, const int* __restrict__ pairs, float* __restrict__ out)
{
  int pe = pairs[blockIdx.y];
  int b = pe >> 4, e = pe & 15, ty = e % 3;
  int nx = (ty == 0) ? 48 : ((ty == 1) ? 96 : 6);
  if ((int)blockIdx.x >= nx) return;
  float gt = gates[b*NE + e];
  int ocg = (ty == 2) ? blockIdx.x : (blockIdx.x % 6);
  int band = (ty == 2) ? 0 : (blockIdx.x / 6);
  int yb = band*8;
  int tid = threadIdx.x;

  __shared__ __align__(16) float smem[3456 + 9216];
  float* wl = smem; float* pa = smem + 3456;
  const float4* wv4 = (const float4*)wl;
  const float* wg = w2 + (size_t)e*CC*CC*9 + (size_t)(ocg*8)*CC*9;
  for (int i = tid; i < 3456; i += 256){
    int ic = i/72, r2 = i%72, k = r2/8, j = r2%8;
    wl[i] = wg[((size_t)j*CC + ic)*9 + k];
  }
  float bb[8];
#pragma unroll
  for (int j = 0; j < 8; j++) bb[j] = b2[e*CC + ocg*8 + j];
  float* ob = out + (size_t)b*CC*NPIX;

  if (ty == 0){
    const float* src = hslot((float*)hbase, e, b, 4096);
    int r = tid >> 5, xp = (tid & 31)*2;
    float a0[8], a1[8];
#pragma unroll
    for (int j = 0; j < 8; j++){ a0[j] = bb[j]; a1[j] = bb[j]; }
    int ldso[10], srco[10];
#pragma unroll
    for (int q = 0; q < 10; q++){
      int i = tid + 256*q;
      int icl = i/640, rem = i%640, rr = rem>>6, cc = rem&63;
      int s = yb - 1 + rr;
      ldso[q] = icl*650 + rr*65 + cc;
      srco[q] = ((unsigned)s < 64u) ? (icl*4096 + s*64 + cc) : -1;
    }
    float st[10];
#pragma unroll
    for (int q = 0; q < 10; q++) st[q] = (srco[q] >= 0) ? src[srco[q]] : 0.f;
#pragma unroll
    for (int q = 0; q < 10; q++) pa[ldso[q]] = st[q];
    __syncthreads();
    for (int icg = 0; icg < 12; icg++){
      if (icg < 11){
        const float* s2 = src + (size_t)(icg+1)*4*4096;
#pragma unroll
        for (int q = 0; q < 10; q++) st[q] = (srco[q] >= 0) ? s2[srco[q]] : 0.f;
      }
      const float* pcur = pa + (icg & 1)*2600;
#pragma unroll
      for (int icl = 0; icl < 4; icl++){
        const float* pp = pcur + icl*650 + r*65;
        float zz[3][4];
#pragma unroll
        for (int dy = 0; dy < 3; dy++)
#pragma unroll
          for (int dx = 0; dx < 4; dx++){
            int xx = xp - 1 + dx;
            zz[dy][dx] = ((unsigned)xx < 64u) ? pp[dy*65 + xx] : 0.f;
          }
        int wb = ((icg*4+icl)*9)*2;
#pragma unroll
        for (int k = 0; k < 9; k++){
          float4 _w0 = wv4[wb + k*2], _w1 = wv4[wb + k*2 + 1];
          ACC8(a0, zz[k/3][k%3]);
          ACC8(a1, zz[k/3][k%3+1]);
        }
      }
      if (icg < 11){
        float* pnext = pa + ((icg+1) & 1)*2600;
#pragma unroll
        for (int q = 0; q < 10; q++) pnext[ldso[q]] = st[q];
      }
      __syncthreads();
    }
    int p0 = (yb + r)*64 + xp;
#pragma unroll
    for (int j = 0; j < 8; j++){
      int oc = ocg*8 + j;
      atomicAdd(&ob[(size_t)oc*4096 + p0],     gt*a0[j]);
      atomicAdd(&ob[(size_t)oc*4096 + p0 + 1], gt*a1[j]);
    }
  } else if (ty == 1){
    // 2x2 quad per thread; maxpool fully in-register
    const float* src = hslot((float*)hbase, e, b, 16384);
    int qr = tid >> 6, qx = (tid & 63)*2;
    float ac[4][8];
#pragma unroll
    for (int i = 0; i < 4; i++)
#pragma unroll
      for (int j = 0; j < 8; j++) ac[i][j] = bb[j];
    int ldso[10], srco[10];
#pragma unroll
    for (int q = 0; q < 10; q++){
      int i = tid + 256*q;
      int icl = i/1280, rem = i%1280, rr = rem>>7, cc = rem&127;
      int s = yb - 1 + rr;
      ldso[q] = icl*1290 + rr*129 + cc;
      srco[q] = ((unsigned)s < 128u) ? (icl*16384 + s*128 + cc) : -1;
    }
    float st[10];
#pragma unroll
    for (int q = 0; q < 10; q++) st[q] = (srco[q] >= 0) ? src[srco[q]] : 0.f;
#pragma unroll
    for (int q = 0; q < 10; q++) pa[ldso[q]] = st[q];
    __syncthreads();
    for (int icg = 0; icg < 24; icg++){
      if (icg < 23){
        const float* s2 = src + (size_t)(icg+1)*2*16384;
#pragma unroll
        for (int q = 0; q < 10; q++) st[q] = (srco[q] >= 0) ? s2[srco[q]] : 0.f;
      }
      const float* pcur = pa + (icg & 1)*2580;
#pragma unroll
      for (int icl = 0; icl < 2; icl++){
        const float* pp = pcur + icl*1290;
        float zz[4][4];
#pragma unroll
        for (int dy = 0; dy < 4; dy++)
#pragma unroll
          for (int dx = 0; dx < 4; dx++){
            int xx = qx + dx - 1;
            zz[dy][dx] = ((unsigned)xx < 128u) ? pp[(2*qr + dy)*129 + xx] : 0.f;
          }
        int wb = ((icg*2+icl)*9)*2;
#pragma unroll
        for (int k = 0; k < 9; k++){
          float4 _w0 = wv4[wb + k*2], _w1 = wv4[wb + k*2 + 1];
          int ky = k/3, kx = k%3;
          ACC8(ac[0], zz[ky][kx]);
          ACC8(ac[1], zz[ky][kx+1]);
          ACC8(ac[2], zz[ky+1][kx]);
          ACC8(ac[3], zz[ky+1][kx+1]);
        }
      }
      if (icg < 23){
        float* pnext = pa + ((icg+1) & 1)*2580;
#pragma unroll
        for (int q = 0; q < 10; q++) pnext[ldso[q]] = st[q];
      }
      __syncthreads();
    }
    int pr = (yb >> 1) + qr, pc = tid & 63;
#pragma unroll
    for (int j = 0; j < 8; j++){
      float m = fmaxf(fmaxf(ac[0][j], ac[1][j]), fmaxf(ac[2][j], ac[3][j]));
      atomicAdd(&ob[(size_t)(ocg*8 + j)*4096 + pr*64 + pc], gt*m);
    }
  } else {
    // whole 32x32 image per block; bilinear-up fused
    const float* src = hslot((float*)hbase, e, b, 1024);
    float ac[4][8];
#pragma unroll
    for (int i = 0; i < 4; i++)
#pragma unroll
      for (int j = 0; j < 8; j++) ac[i][j] = bb[j];
    float st[8];
#pragma unroll
    for (int q = 0; q < 8; q++) st[q] = src[tid + 256*q];
#pragma unroll
    for (int q = 0; q < 8; q++) pa[tid + 256*q] = st[q];
    __syncthreads();
    for (int icg = 0; icg < 24; icg++){
      if (icg < 23){
        const float* s2 = src + (size_t)(icg+1)*2*1024;
#pragma unroll
        for (int q = 0; q < 8; q++) st[q] = s2[tid + 256*q];
      }
      const float* pcur = pa + (icg & 1)*2048;
#pragma unroll
      for (int icl = 0; icl < 2; icl++){
        const float* pp = pcur + icl*1024;
        int wb0 = ((icg*2+icl)*9)*2;
#pragma unroll
        for (int ii = 0; ii < 4; ii++){
          int l = tid + 256*ii;
          int oy = l >> 5, ox = l & 31;
#pragma unroll
          for (int k = 0; k < 9; k++){
            int ky = k/3, kx = k%3;
            int yy = oy + ky - 1, xx = ox + kx - 1;
            float z = ((unsigned)yy < 32u && (unsigned)xx < 32u) ? pp[yy*32 + xx] : 0.f;
            float4 _w0 = wv4[wb0 + k*2], _w1 = wv4[wb0 + k*2 + 1];
            ACC8(ac[ii], z);
          }
        }
      }
      if (icg < 23){
        float* pnext = pa + ((icg+1) & 1)*2048;
#pragma unroll
        for (int q = 0; q < 8; q++) pnext[tid + 256*q] = st[q];
      }
      __syncthreads();
    }
    float* he = pa;   // patch dead after final barrier; reuse [1024][9]
#pragma unroll
    for (int ii = 0; ii < 4; ii++){
      int l = tid + 256*ii;
#pragma unroll
      for (int j = 0; j < 8; j++) he[l*9 + j] = ac[ii][j];
    }
    __syncthreads();
    for (int it = 0; it < 16; it++){
      int op = tid + 256*it;
      int y = op >> 6, x = op & 63;
      int y0,y1,x0,x1; float wy0,wy1,wx0,wx1;
      bl_coord(y, y0, y1, wy0, wy1);
      bl_coord(x, x0, x1, wx0, wx1);
#pragma unroll
      for (int j = 0; j < 8; j++){
        float v = wy0*(wx0*he[(y0*32+x0)*9+j] + wx1*he[(y0*32+x1)*9+j])
                + wy1*(wx0*he[(y1*32+x0)*9+j] + wx1*he[(y1*32+x1)*9+j]);
        atomicAdd(&ob[(size_t)(ocg*8 + j)*NPIX + op], gt*v);
      }
    }
  }
}

// ---------------- launch ---------------------------------------------------------
extern "C" void kernel_launch(void* const* d_in, const int* in_sizes, int n_in,
                              void* d_out, int out_size, void* d_ws, size_t ws_size,
                              hipStream_t stream) {
  const float* x      = (const float*)d_in[0];
  const float* text   = (const float*)d_in[1];
  const float* ln1w   = (const float*)d_in[3];
  const float* ln1b   = (const float*)d_in[4];
  const float* ln2w   = (const float*)d_in[5];
  const float* ln2b   = (const float*)d_in[6];
  const float* qkvw   = (const float*)d_in[7];
  const float* qkvdw  = (const float*)d_in[8];
  const float* projw  = (const float*)d_in[9];
  const float* routw  = (const float*)d_in[10];
  const float* gwx    = (const float*)d_in[11];
  const float* gwt    = (const float*)d_in[12];
  const float* ew1    = (const float*)d_in[13];
  const float* eb1    = (const float*)d_in[14];
  const float* ew2    = (const float*)d_in[15];
  const float* eb2    = (const float*)d_in[16];
  float* out = (float*)d_out;

  float* wsf = (float*)d_ws;
  float* y2      = wsf;                      // 786432 f
  float* pooled  = wsf + 786432;             // 192
  float* gates   = wsf + 786624;             // 64
  int*   pairs   = (int*)(wsf + 786688);     // 8 ints
  float* F       = wsf + 786944;
  float* qkv_raw = F;                        // 2359296
  float* qkv_dw  = F + 2359296;              // 2359296
  float* rl      = F + 4718592;              // 131072
  float* gmask   = F + 4849664;              // 131072
  float* attnout = F + 4980736;              // 786432
  float* part    = F + 5767168;              // 12288
  float* smg     = F + 5779456;              // 1152
  float* hbase   = F;                        // expert h slots (21430272 f)

  k_ln_qkv<<<dim3(16, SB, 6), 256, 0, stream>>>(x, ln1w, ln1b, qkvw, routw, qkv_raw, rl);
  k_dwconv<<<dim3(16, 144, SB), 256, 0, stream>>>(qkv_raw, qkvdw, qkv_dw);
  k_router_gates<<<dim3(64), 256, 0, stream>>>(rl, gmask);
  k_attn_part<<<dim3(8, NH, SB), 256, 0, stream>>>(qkv_dw, part);
  k_attn_soft<<<dim3(NH, SB), 64, 0, stream>>>(part, smg);
  k_attn_apply<<<dim3(16, NH, SB), 256, 0, stream>>>(qkv_dw, smg, gmask, attnout);
  k_proj_ln2<<<dim3(64, SB), 64, 0, stream>>>(attnout, x, projw, ln2w, ln2b, out, y2);
  k_pool<<<dim3(SB*CC), 256, 0, stream>>>(y2, pooled);
  k_moe_gate<<<dim3(1), 64, 0, stream>>>(pooled, text, gwx, gwt, gates, pairs);

  k_econv1u<<<dim3(96, 8), 256, 0, stream>>>(y2, ew1, eb1, pairs, hbase);
  k_econv2u<<<dim3(96, 8), 256, 0, stream>>>(hbase, ew2, eb2, gates, pairs, out);

  (void)in_sizes; (void)n_in; (void)out_size; (void)ws_size;
}